// Round 5
// baseline (181.055 us; speedup 1.0000x reference)
//
#include <hip/hip_runtime.h>
#include <math.h>

// Depth collapses to d=0 (x[:, :, 0:1] slicing): conv1d -> w[3]*xi+b,
// scan at d=0 -> hs[0]=BX[0] (A_log unused), y = xi*(delta*sum(B*C)+D).
#define NB   2
#define CM   96      // D_MODEL
#define CI   192     // D_INNER
#define CO   384     // 2*D_INNER
#define HP   24
#define WP   24
#define PX   576
#define DTR  6
#define NDBC 38
#define CSPLIT 8
#define CCH  12      // input channels per conv chunk (96/CSPLIT)
#define WROW 109     // padded LDS weight row (109 coprime-ish: 2-way bank alias only)

__device__ __forceinline__ float siluf(float x){ return x / (1.f + expf(-x)); }
__device__ __forceinline__ float softplusf(float x){ return x > 20.f ? x : log1pf(expf(x)); }

// ---- conv: fused rmsnorm + 3x3 conv (pad 1), fp32, self-contained weight staging.
// grid (NB*HP, 6 o-groups, CSPLIT c-chunks), block 256 (4 waves x 6-px strips).
// acc layout: [cs][n][px][o]
__global__ __launch_bounds__(256, 4) void conv_k(
    const float* __restrict__ x, long nStr, long cStr,
    const float* __restrict__ nw,
    const float* __restrict__ ipw,     // layer base: [o=384][c=96][k=9]
    float* __restrict__ acc)
{
    __shared__ float wgt[64*WROW];     // [o_local][109] (108 used)  27.9 KB
    __shared__ float hs[CCH][3][28];   // 4.0 KB, rows 16B-aligned
    __shared__ float scl[CCH][3];
    int bx = blockIdx.x;
    int og = blockIdx.y;
    int cs = blockIdx.z;
    int n  = bx / HP, hh = bx % HP;
    int tid = threadIdx.x;
    int c0 = cs*CCH;

    // stage weights: 64 rows x 108 contiguous floats, coalesced float4 loads
    for (int idx = tid; idx < 64*27; idx += 256){
        int ol = idx / 27, q = idx % 27;
        const float* src = ipw + (long)(og*64 + ol)*(CM*9) + cs*(CCH*9) + q*4;
        float4 v = *(const float4*)src;
        float* dst = &wgt[ol*WROW + q*4];
        dst[0] = v.x; dst[1] = v.y; dst[2] = v.z; dst[3] = v.w;
    }

    if (tid < CCH*3){
        int c = tid/3, j = tid%3;
        int row = hh + j - 1;
        float s = 0.f;
        if (row >= 0 && row < HP){
            const float* xp = x + (long)n*nStr + (long)(c0+c)*cStr + row*WP;
            #pragma unroll
            for (int w = 0; w < WP; w++){ float v = xp[w]; s += v*v; }
            s = rsqrtf(s*(1.0f/WP) + 1e-5f) * nw[c0+c];
        }
        scl[c][j] = s;
    }
    __syncthreads();

    for (int idx = tid; idx < CCH*3*28; idx += 256){
        int c = idx/84; int rem = idx%84; int j = rem/28; int wc = rem%28;
        int row = hh + j - 1;
        float v = 0.f;
        if (row >= 0 && row < HP && wc >= 1 && wc <= WP)
            v = x[(long)n*nStr + (long)(c0+c)*cStr + row*WP + (wc-1)] * scl[c][j];
        hs[c][j][wc] = v;
    }
    __syncthreads();

    int ol = tid & 63;
    int o  = og*64 + ol;
    int x0 = (tid >> 6) * 6;           // even -> 8B-aligned float2 loads
    float a0[6] = {0,0,0,0,0,0};
    const float* wrow = &wgt[ol*WROW];

    for (int c = 0; c < CCH; c++){
        const float* wk = wrow + c*9;
        float w0 = wk[0], w1 = wk[1], w2 = wk[2];
        float w3 = wk[3], w4 = wk[4], w5 = wk[5];
        float w6 = wk[6], w7 = wk[7], w8 = wk[8];
        float r0v[8], r1v[8], r2v[8];
        #pragma unroll
        for (int i = 0; i < 4; i++){
            float2 p0 = *(const float2*)(&hs[c][0][x0] + 2*i);
            float2 p1 = *(const float2*)(&hs[c][1][x0] + 2*i);
            float2 p2 = *(const float2*)(&hs[c][2][x0] + 2*i);
            r0v[2*i] = p0.x; r0v[2*i+1] = p0.y;
            r1v[2*i] = p1.x; r1v[2*i+1] = p1.y;
            r2v[2*i] = p2.x; r2v[2*i+1] = p2.y;
        }
        #pragma unroll
        for (int p = 0; p < 6; p++){
            a0[p] += w0*r0v[p] + w1*r0v[p+1] + w2*r0v[p+2]
                   + w3*r1v[p] + w4*r1v[p+1] + w5*r1v[p+2]
                   + w6*r2v[p] + w7*r2v[p+1] + w8*r2v[p+2];
        }
    }

    float* ap = acc + ((long)(cs*NB + n)*PX + hh*WP + x0)*CO + o;
    #pragma unroll
    for (int p = 0; p < 6; p++) ap[p*CO] = a0[p];
}

// ---- ssmproj: sum partials -> conv1d tap + SiLU gates -> x_proj/dt/BC -> gate ->
//               out_proj + residual. block 256 = 4 waves = 4 pixels; grid NB*PX/4.
__global__ __launch_bounds__(256, 4) void ssmproj_k(
    const float* __restrict__ acc,
    const float* __restrict__ c1w, const float* __restrict__ c1b,
    const float* __restrict__ xpw, const float* __restrict__ dtw,
    const float* __restrict__ dtb, const float* __restrict__ Dp,
    const float* __restrict__ opw,   // layer base: [m=96][c=192]
    const float* __restrict__ xres, long nStrR, long cStrR,
    float* __restrict__ dst)
{
    __shared__ float gl[4][CI];
    int wave = threadIdx.x >> 6, lane = threadIdx.x & 63;
    int p0 = blockIdx.x*4;
    int p  = p0 + wave;
    int n  = p / PX, px = p % PX;

    float xi[3], sz[3];
    #pragma unroll
    for (int t = 0; t < 3; t++){
        int c = lane + 64*t;
        float xr = 0.f, zr = 0.f;
        #pragma unroll
        for (int q = 0; q < CSPLIT; q++){
            const float* ap = acc + ((long)(q*NB + n)*PX + px)*CO;
            xr += ap[c]; zr += ap[CI + c];
        }
        xi[t] = siluf(xr*c1w[c*4 + 3] + c1b[c]);
        sz[t] = siluf(zr);
    }

    float dbc[NDBC];
    #pragma unroll
    for (int j = 0; j < NDBC; j++){
        float s = 0.f;
        #pragma unroll
        for (int t = 0; t < 3; t++) s += xi[t]*xpw[j*CI + lane + 64*t];
        dbc[j] = s;
    }
    #pragma unroll
    for (int step = 1; step < 64; step <<= 1){
        #pragma unroll
        for (int j = 0; j < NDBC; j++) dbc[j] += __shfl_xor(dbc[j], step, 64);
    }
    float BC = 0.f;
    #pragma unroll
    for (int s = 0; s < 16; s++) BC += dbc[6+s]*dbc[22+s];

    #pragma unroll
    for (int t = 0; t < 3; t++){
        int c = lane + 64*t;
        float dl = dtb[c];
        #pragma unroll
        for (int r = 0; r < DTR; r++) dl += dbc[r]*dtw[c*DTR + r];
        dl = softplusf(dl);
        gl[wave][c] = xi[t]*(dl*BC + Dp[c])*sz[t];
    }
    __syncthreads();

    for (int idx = threadIdx.x; idx < 4*CM; idx += 256){
        int pl = idx / CM, m = idx % CM;
        int pp = p0 + pl;
        int nn = pp / PX, ppx = pp % PX;
        const float* g = gl[pl];
        const float* wr = opw + m*CI;          // per-lane row, 16B-aligned, L2-hot
        float s0 = 0.f, s1 = 0.f, s2 = 0.f, s3 = 0.f;
        for (int c = 0; c < CI; c += 4){
            float4 gv = *(const float4*)&g[c];
            float4 wv = *(const float4*)&wr[c];
            s0 += gv.x*wv.x; s1 += gv.y*wv.y; s2 += gv.z*wv.z; s3 += gv.w*wv.w;
        }
        float s = (s0+s1) + (s2+s3);
        s += xres[(long)nn*nStrR + (long)m*cStrR + ppx];
        dst[(nn*CM + m)*PX + ppx] = s;
    }
}

extern "C" void kernel_launch(void* const* d_in, const int* in_sizes, int n_in,
                              void* d_out, int out_size, void* d_ws, size_t ws_size,
                              hipStream_t stream) {
    const float* x_in = (const float*)d_in[0];   // (2,96,8,24,24)
    const float* ipw  = (const float*)d_in[1];   // (2,384,96,1,3,3)
    const float* c1w  = (const float*)d_in[2];   // (2,192,1,4,1,1)
    const float* c1b  = (const float*)d_in[3];   // (2,192)
    const float* xpw  = (const float*)d_in[4];   // (2,38,192)
    const float* dtw  = (const float*)d_in[5];   // (2,192,6)
    const float* dtb  = (const float*)d_in[6];   // (2,192)
    // d_in[7] = A_log: unused at depth 0 (multiplies h[-1]=0)
    const float* Dp   = (const float*)d_in[8];   // (2,192)
    const float* opw  = (const float*)d_in[9];   // (2,96,192)
    const float* nw   = (const float*)d_in[10];  // (2,1,96,1,1,1)

    float* acc = (float*)d_ws;                   // 8*2*576*384 f = 14.2 MB
    float* x1  = acc + (long)CSPLIT*NB*PX*CO;    // 110592 f

    // ---- layer 0 (input: depth-0 slice of x, strides of (2,96,8,24,24))
    conv_k<<<dim3(NB*HP, 6, CSPLIT), 256, 0, stream>>>(
        x_in, 96L*8*PX, 8L*PX, nw, ipw, acc);
    ssmproj_k<<<NB*PX/4, 256, 0, stream>>>(
        acc, c1w, c1b, xpw, dtw, dtb, Dp, opw,
        x_in, 96L*8*PX, 8L*PX, x1);

    // ---- layer 1 (input x1 packed (2,96,24,24); writes final output)
    conv_k<<<dim3(NB*HP, 6, CSPLIT), 256, 0, stream>>>(
        x1, 96L*PX, (long)PX, nw + CM, ipw + 2L*CO*CM*9/2, acc);
    ssmproj_k<<<NB*PX/4, 256, 0, stream>>>(
        acc, c1w + CI*4, c1b + CI, xpw + NDBC*CI, dtw + CI*DTR, dtb + CI, Dp + CI,
        opw + CM*CI,
        x1, 96L*PX, (long)PX, (float*)d_out);
}